// Round 3
// baseline (312.319 us; speedup 1.0000x reference)
//
#include <hip/hip_runtime.h>
#include <hip/hip_bf16.h>
#include <hip/hip_cooperative_groups.h>

namespace cg = cooperative_groups;

#define SEQ 2048
#define HID 1024
#define NH 16
#define HD 64
#define QKVLD 3072

typedef __attribute__((ext_vector_type(8))) short bf16x8;
typedef __attribute__((ext_vector_type(4))) float f32x4;

__device__ __forceinline__ unsigned short f2bf(float f) {
  unsigned int x = __float_as_uint(f);
  x += 0x7fffu + ((x >> 16) & 1u);
  return (unsigned short)(x >> 16);
}

// packed f32x2 -> bf16x2 (v_cvt_pk_bf16_f32, RNE - same rounding as f2bf)
__device__ __forceinline__ unsigned int pkbf(float a, float b) {
  union { __hip_bfloat162 h2; unsigned int u; } cvt;
  cvt.h2 = __float22bfloat162_rn(make_float2(a, b));
  return cvt.u;
}

__device__ __forceinline__ void gld_lds16(const void* g, void* l) {
  __builtin_amdgcn_global_load_lds((__attribute__((address_space(1))) void*)g,
                                   (__attribute__((address_space(3))) void*)l, 16, 0, 0);
}

// ============ FUSED PIPELINE: one cooperative kernel, grid.sync between phases ============
// Rationale: three rounds of compute-side changes (K-loop schedule, dbuf, LDS swizzle
// width) were all neutral at ~123-125 us while structural cycle counts put the four
// kernels at ~25-40 us total -> the measured time is dominated by per-launch overhead
// (4 dependent launches) + harness fills. Fusing removes 3 inter-kernel gaps and one
// launch. grid.sync() (cooperative) provides execution barrier + device-scope fences
// for cross-XCD visibility of intermediates (Guideline 16).
// Co-residency: 512 blocks x 256 thr, 56 KB LDS -> exactly 2 blocks/CU on 256 CUs.

// ---------------- phase 0: X f32->bf16 + weight transposes f32->bf16^T ----------------
// 512 blocks: each does 2 X-chunks (2048 elems each) + 8 weight 32x32 transpose tiles.
// z = wt>>10: 0=Wq (scaled 0.125 = 1/sqrt(HD)), 1=Wk, 2=Wv, 3=Wo.
__device__ void prep_body(int bid, int tid, char* smem, const float* X, const float* Wq,
                          const float* Wk, const float* Wv, const float* Wo,
                          unsigned short* Xb, unsigned short* WtQKV, unsigned short* WtO) {
  {
    size_t base0 = (size_t)(bid * 2) * 2048 + (size_t)tid * 4;
#pragma unroll
    for (int u = 0; u < 2; u++) {
#pragma unroll
      for (int half = 0; half < 2; half++) {
        size_t base = base0 + u * 2048 + half * 1024;
        float4 v = *(const float4*)(X + base);
        *(uint2*)(Xb + base) = make_uint2(pkbf(v.x, v.y), pkbf(v.z, v.w));
      }
    }
  }
  float(*tile)[33] = (float(*)[33])smem;
  const int tx = tid & 31, ty = tid >> 5;
  for (int i = 0; i < 8; i++) {
    int wt = bid * 8 + i;
    int z = wt >> 10, t = wt & 1023;
    const float* S = (z == 0) ? Wq : (z == 1) ? Wk : (z == 2) ? Wv : Wo;
    unsigned short* D = (z < 3) ? (WtQKV + (size_t)z * HID * HID) : WtO;
    const float scale = (z == 0) ? 0.125f : 1.0f;
    int r0 = (t >> 5) * 32, c0 = (t & 31) * 32;
    __syncthreads();  // protect tile buffer reuse across iterations
#pragma unroll
    for (int k = 0; k < 4; k++)
      tile[ty + k * 8][tx] = S[(size_t)(r0 + ty + k * 8) * HID + c0 + tx];
    __syncthreads();
#pragma unroll
    for (int k = 0; k < 4; k++)
      D[(size_t)(c0 + ty + k * 8) * HID + r0 + tx] = f2bf(scale * tile[tx][ty + k * 8]);
  }
}

// ---------------- GEMM body: C[M,N] = A[M,K](bf16) * Bt[N,K](bf16)^T ----------------
// Identical to the verified round-2 kernel: tile (MI*32) x BN, BK=64, 4 waves 2x2,
// double-buffered prefetch-before-compute, one barrier per K-step, full 8-chunk XOR
// swizzle (slot = chunk ^ (row&7); staging keeps LINEAR LDS dest, inverse-permuted
// global source). XCD rect decode from flat lin. OUT==0: f32 row-major. OUT==2: bf16
// row-major for cols<2048, transposed uint2 into Vout for cols>=2048 (V block).
template <int MI, int BN, int BK, int RW, int XB, int OUT>
__device__ void gemm_body(int lin, int tid, char* smem, const unsigned short* A,
                          const unsigned short* Bt, void* Cout, unsigned short* Vout,
                          int M, int N, int K) {
  constexpr int NI = BN / 32;
  constexpr int TM = MI * 32;
  constexpr int KC = BK / 8;
  static_assert(KC == 8, "8-chunk XOR swizzle requires BK=64");
  unsigned short* As = (unsigned short*)smem;             // [2][TM*BK]
  unsigned short* Bs = As + 2 * TM * BK;                  // [2][BN*BK]
  const int lane = tid & 63;
  const int w = tid >> 6;
  const int wm = w >> 1, wn = w & 1;
  const int quad = lane >> 4, l16 = lane & 15;

  const int xcd = lin & 7, idx = lin >> 3;
  const int bx = (xcd & 3) * RW + (idx % RW);
  const int by = (xcd >> 2) * (XB / RW) + (idx / RW);
  const int bm = by * TM, bn = bx * BN;

  f32x4 acc[MI][NI] = {};

  auto stage = [&](int k0, int b) {
#pragma unroll
    for (int c = tid; c < TM * KC; c += 256) {
      int r = c / KC, kc = c % KC;
      int g = kc ^ (r & 7);
      gld_lds16(A + (size_t)(bm + r) * K + k0 + g * 8, As + b * TM * BK + c * 8);
    }
#pragma unroll
    for (int c = tid; c < BN * KC; c += 256) {
      int r = c / KC, kc = c % KC;
      int g = kc ^ (r & 7);
      gld_lds16(Bt + (size_t)(bn + r) * K + k0 + g * 8, Bs + b * BN * BK + c * 8);
    }
  };

  const int NT = K / BK;
  stage(0, 0);
  __syncthreads();

  for (int t = 0; t < NT; ++t) {
    if (t + 1 < NT) stage((t + 1) * BK, (t + 1) & 1);
    const unsigned short* AsB = As + (t & 1) * TM * BK;
    const unsigned short* BsB = Bs + (t & 1) * BN * BK;
#pragma unroll
    for (int ks = 0; ks < BK / 32; ks++) {
      bf16x8 af[MI], bfr[NI];
#pragma unroll
      for (int mi = 0; mi < MI; mi++) {
        int m = wm * (MI * 16) + mi * 16 + l16;
        af[mi] = *(const bf16x8*)(AsB + (m * KC + ((ks * 4 + quad) ^ (m & 7))) * 8);
      }
#pragma unroll
      for (int ni = 0; ni < NI; ni++) {
        int n = wn * (BN / 2) + ni * 16 + l16;
        bfr[ni] = *(const bf16x8*)(BsB + (n * KC + ((ks * 4 + quad) ^ (n & 7))) * 8);
      }
#pragma unroll
      for (int mi = 0; mi < MI; mi++)
#pragma unroll
        for (int ni = 0; ni < NI; ni++)
          acc[mi][ni] = __builtin_amdgcn_mfma_f32_16x16x32_bf16(af[mi], bfr[ni], acc[mi][ni], 0, 0, 0);
    }
    __syncthreads();
  }

#pragma unroll
  for (int mi = 0; mi < MI; mi++) {
#pragma unroll
    for (int ni = 0; ni < NI; ni++) {
      int row = bm + wm * (MI * 16) + mi * 16 + quad * 4;
      int col = bn + wn * (BN / 2) + ni * 16 + l16;
      if (OUT == 0) {
#pragma unroll
        for (int r = 0; r < 4; r++)
          ((float*)Cout)[(size_t)(row + r) * N + col] = acc[mi][ni][r];
      } else {
        if (col < 2 * HID) {
#pragma unroll
          for (int r = 0; r < 4; r++)
            ((unsigned short*)Cout)[(size_t)(row + r) * N + col] = f2bf(acc[mi][ni][r]);
        } else {
          *(uint2*)(Vout + (size_t)(col - 2 * HID) * SEQ + row) =
              make_uint2(pkbf(acc[mi][ni][0], acc[mi][ni][1]),
                         pkbf(acc[mi][ni][2], acc[mi][ni][3]));
        }
      }
    }
  }
}

// ---------------- phase 2: sparse flash attention (S^T form, fixed-max softmax) ----------------
// Verbatim from the verified round-2 kernel; lin = flat bid. Double-buffered K/V LDS
// tiles, one barrier/tile, full 8-chunk XOR swizzle, per-wave P^T in LDS, compact
// global-column tile last, quad-reduce of lsum, normalized uint2 store.
__device__ void attn_body(int lin, int tid, char* smem, const unsigned short* QKV,
                          const unsigned short* VtG, unsigned short* AttO) {
  unsigned short* Ks = (unsigned short*)smem;   // [2][64*64]
  unsigned short* Vt = Ks + 2 * 64 * 64;        // [2][64*64]
  unsigned short* Pw = Vt + 2 * 64 * 64;        // [4][16*72]
  const int xcd = lin & 7, slot = lin >> 3;
  const int h = slot >> 2;
  const int qbase = (xcd * 4 + (slot & 3)) * 64;
  const int lane = tid & 63, w = tid >> 6;
  const int quad = lane >> 4, l16 = lane & 15;
  const int qrow0 = qbase + w * 16;
  unsigned short* pws = Pw + w * 16 * 72;

  bf16x8 aq[2];
  {
    const unsigned short* qp = QKV + (size_t)(qrow0 + l16) * QKVLD + h * HD + quad * 8;
    aq[0] = *(const bf16x8*)qp;
    aq[1] = *(const bf16x8*)(qp + 32);
  }

  f32x4 accO[4] = {};
  float lsum = 0.f;

  const int jlo = (qbase >= 512) ? (qbase - 512) : 0;
  const int ng = (jlo > 0) ? ((jlo + 511) >> 9) : 0;
  const int ntl = ((qbase - jlo) >> 6) + 1;

  auto stage = [&](int j0, int b) {
#pragma unroll
    for (int c = tid; c < 512; c += 256) {
      int r = c >> 3, kc = c & 7;
      int g = kc ^ (r & 7);
      gld_lds16(QKV + (size_t)(j0 + r) * QKVLD + HID + h * HD + g * 8, Ks + b * 4096 + c * 8);
      gld_lds16(VtG + (size_t)(h * HD + r) * SEQ + j0 + g * 8, Vt + b * 4096 + c * 8);
    }
  };

  stage(jlo, 0);
  __syncthreads();

  for (int t = 0; t < ntl; t++) {
    if (t + 1 < ntl) stage(jlo + (t + 1) * 64, (t + 1) & 1);
    const unsigned short* KsB = Ks + (t & 1) * 4096;
    const unsigned short* VtB = Vt + (t & 1) * 4096;
    const int j0 = jlo + t * 64;

    f32x4 s[4] = {};
#pragma unroll
    for (int nj = 0; nj < 4; nj++) {
      int row = nj * 16 + l16;
#pragma unroll
      for (int ks = 0; ks < 2; ks++) {
        bf16x8 ak = *(const bf16x8*)(KsB + (row * 8 + ((ks * 4 + quad) ^ (row & 7))) * 8);
        s[nj] = __builtin_amdgcn_mfma_f32_16x16x32_bf16(ak, aq[ks], s[nj], 0, 0, 0);
      }
    }

    const bool isdiag = (t == ntl - 1);
    const bool istrail = (t == 0) && (qbase >= 512);
    const int trailg = (istrail && ((j0 & 511) == 0)) ? 1 : 0;
    const int db = qrow0 + l16 - j0 - quad * 4;
#pragma unroll
    for (int nj = 0; nj < 4; nj++) {
      float p[4];
#pragma unroll
      for (int r = 0; r < 4; r++) {
        float x = s[nj][r];
        int d = db - nj * 16 - r;
        bool valid = true;
        if (isdiag) valid = (d >= 0);
        else if (istrail) valid = (d <= 512) || (trailg && (nj * 16 + quad * 4 + r) == 0);
        x = valid ? x : -1e30f;
        p[r] = __expf(x);
        lsum += p[r];
      }
      *(uint2*)(pws + l16 * 72 + nj * 16 + quad * 4) =
          make_uint2(pkbf(p[0], p[1]), pkbf(p[2], p[3]));
    }

#pragma unroll
    for (int kk = 0; kk < 2; kk++) {
      bf16x8 bp = *(const bf16x8*)(pws + l16 * 72 + kk * 32 + quad * 8);
#pragma unroll
      for (int nd = 0; nd < 4; nd++) {
        int row = nd * 16 + l16;
        bf16x8 av = *(const bf16x8*)(VtB + (row * 8 + ((kk * 4 + quad) ^ (row & 7))) * 8);
        accO[nd] = __builtin_amdgcn_mfma_f32_16x16x32_bf16(av, bp, accO[nd], 0, 0, 0);
      }
    }
    __syncthreads();
  }

  if (ng > 0) {
    if (tid < ng * 8) {
      int r = tid >> 3, kc = tid & 7;
      int g = kc ^ (r & 7);
      *(uint4*)(Ks + tid * 8) =
          *(const uint4*)(QKV + ((size_t)r << 9) * QKVLD + HID + h * HD + g * 8);
    }
    if (tid < ng * 64) {
      int d = tid & 63, c = tid >> 6;
      Vt[(d * 8 + (d & 7)) * 8 + c] = VtG[(size_t)(h * HD + d) * SEQ + ((size_t)c << 9)];
    }
    __syncthreads();
    f32x4 s0 = {};
#pragma unroll
    for (int ks = 0; ks < 2; ks++) {
      bf16x8 ak = *(const bf16x8*)(Ks + (l16 * 8 + ((ks * 4 + quad) ^ (l16 & 7))) * 8);
      s0 = __builtin_amdgcn_mfma_f32_16x16x32_bf16(ak, aq[ks], s0, 0, 0, 0);
    }
    float p[4];
#pragma unroll
    for (int r = 0; r < 4; r++) {
      p[r] = ((quad * 4 + r) < ng) ? __expf(s0[r]) : 0.f;
      lsum += p[r];
    }
    *(uint2*)(pws + l16 * 72 + quad * 4) = make_uint2(pkbf(p[0], p[1]), pkbf(p[2], p[3]));
    *(uint2*)(pws + l16 * 72 + 16 + quad * 4) = make_uint2(0, 0);
    bf16x8 bp = *(const bf16x8*)(pws + l16 * 72 + quad * 8);
#pragma unroll
    for (int nd = 0; nd < 4; nd++) {
      int row = nd * 16 + l16;
      bf16x8 av = *(const bf16x8*)(Vt + (row * 8 + (quad ^ (row & 7))) * 8);
      accO[nd] = __builtin_amdgcn_mfma_f32_16x16x32_bf16(av, bp, accO[nd], 0, 0, 0);
    }
  }

  lsum += __shfl_xor(lsum, 16);
  lsum += __shfl_xor(lsum, 32);
  const float rl = 1.0f / lsum;
  const int i = qrow0 + l16;
#pragma unroll
  for (int nd = 0; nd < 4; nd++) {
    *(uint2*)(AttO + (size_t)i * HID + h * HD + nd * 16 + quad * 4) =
        make_uint2(pkbf(accO[nd][0] * rl, accO[nd][1] * rl),
                   pkbf(accO[nd][2] * rl, accO[nd][3] * rl));
  }
}

// ---------------- the fused cooperative kernel ----------------
__global__ __launch_bounds__(256, 2) void fused(const float* __restrict__ X,
                                                const float* __restrict__ Wq,
                                                const float* __restrict__ Wk,
                                                const float* __restrict__ Wv,
                                                const float* __restrict__ Wo,
                                                float* __restrict__ out,
                                                unsigned short* __restrict__ Xb,
                                                unsigned short* __restrict__ WtQKV,
                                                unsigned short* __restrict__ WtO,
                                                unsigned short* __restrict__ QKV,
                                                unsigned short* __restrict__ VtG,
                                                unsigned short* __restrict__ AttO) {
  // LDS union: P1 gemm dbuf 2*(128+96)*64*2B = 56 KB (max of all phases)
  __shared__ alignas(16) char smem[57344];
  cg::grid_group grid = cg::this_grid();
  const int bid = blockIdx.x;
  const int tid = threadIdx.x;

  prep_body(bid, tid, smem, X, Wq, Wk, Wv, Wo, Xb, WtQKV, WtO);
  grid.sync();
  // QKV proj: 128x96 tiles, XCD rect 8x8 (A 2MB + B 1.5MB per L2)
  gemm_body<4, 96, 64, 8, 64, 2>(bid, tid, smem, Xb, WtQKV, QKV, VtG, SEQ, QKVLD, HID);
  grid.sync();
  attn_body(bid, tid, smem, QKV, VtG, AttO);
  grid.sync();
  // out-proj: 64x64 tiles, XCD rect 4x16 (A 2MB + B 0.5MB per L2)
  gemm_body<2, 64, 64, 4, 64, 0>(bid, tid, smem, AttO, WtO, out, nullptr, SEQ, HID, HID);
}

extern "C" void kernel_launch(void* const* d_in, const int* in_sizes, int n_in,
                              void* d_out, int out_size, void* d_ws, size_t ws_size,
                              hipStream_t stream) {
  const float* X  = (const float*)d_in[0];
  const float* Wq = (const float*)d_in[1];
  const float* Wk = (const float*)d_in[2];
  const float* Wv = (const float*)d_in[3];
  const float* Wo = (const float*)d_in[4];
  float* out = (float*)d_out;

  unsigned short* Xb    = (unsigned short*)d_ws;                  // 2048x1024
  unsigned short* WtQKV = Xb + (size_t)SEQ * HID;                 // 3072x1024
  unsigned short* WtO   = WtQKV + (size_t)QKVLD * HID;            // 1024x1024
  unsigned short* QKV   = WtO + (size_t)HID * HID;                // 2048x3072 (V block unused)
  unsigned short* VtG   = QKV + (size_t)SEQ * QKVLD;              // 1024x2048 (V transposed)
  unsigned short* AttO  = VtG + (size_t)HID * SEQ;                // 2048x1024

  void* args[] = {(void*)&X, (void*)&Wq, (void*)&Wk, (void*)&Wv, (void*)&Wo, (void*)&out,
                  (void*)&Xb, (void*)&WtQKV, (void*)&WtO, (void*)&QKV, (void*)&VtG,
                  (void*)&AttO};
  hipLaunchCooperativeKernel((const void*)fused, dim3(512), dim3(256), args, 0, stream);
}

// Round 4
// 122.166 us; speedup vs baseline: 2.5565x; 2.5565x over previous
//
#include <hip/hip_runtime.h>
#include <hip/hip_bf16.h>

#define SEQ 2048
#define HID 1024
#define NH 16
#define HD 64
#define QKVLD 3072

typedef __attribute__((ext_vector_type(8))) short bf16x8;
typedef __attribute__((ext_vector_type(4))) float f32x4;

__device__ __forceinline__ unsigned short f2bf(float f) {
  unsigned int x = __float_as_uint(f);
  x += 0x7fffu + ((x >> 16) & 1u);
  return (unsigned short)(x >> 16);
}

// packed f32x2 -> bf16x2 (v_cvt_pk_bf16_f32, RNE - same rounding as f2bf)
__device__ __forceinline__ unsigned int pkbf(float a, float b) {
  union { __hip_bfloat162 h2; unsigned int u; } cvt;
  cvt.h2 = __float22bfloat162_rn(make_float2(a, b));
  return cvt.u;
}

__device__ __forceinline__ void gld_lds16(const void* g, void* l) {
  __builtin_amdgcn_global_load_lds((__attribute__((address_space(1))) void*)g,
                                   (__attribute__((address_space(3))) void*)l, 16, 0, 0);
}

// NOTE (R3 post-mortem): single fused cooperative kernel with grid.sync() was
// tried and REGRESSED 123 -> 312 us (steady-state kernel 237 us; ~60 us per
// grid.sync from cross-XCD cache maintenance). Sequential launches are the
// efficient structure on 8-XCD gfx950. This file is the verified R2 version.

// ---------------- prep: z<4 -> weight transpose f32->bf16^T, z==4 -> cvt X ----------------
// z=0: Wq (scaled by 0.125 = 1/sqrt(HD)), z=1: Wk, z=2: Wv, z=3: Wo
__global__ void prep(const float* __restrict__ X, const float* __restrict__ Wq,
                     const float* __restrict__ Wk, const float* __restrict__ Wv,
                     const float* __restrict__ Wo, unsigned short* __restrict__ Xb,
                     unsigned short* __restrict__ WtQKV, unsigned short* __restrict__ WtO) {
  const int z = blockIdx.z;
  if (z == 4) {  // convert X -> bf16, 1024 blocks x 2048 elems
    int bid = blockIdx.y * 32 + blockIdx.x;
    int t = threadIdx.y * 32 + threadIdx.x;
    size_t base = (size_t)bid * 2048 + t * 4;
#pragma unroll
    for (int half = 0; half < 2; half++) {
      float4 v = *(const float4*)(X + base + half * 1024);
      *(uint2*)(Xb + base + half * 1024) = make_uint2(pkbf(v.x, v.y), pkbf(v.z, v.w));
    }
    return;
  }
  __shared__ float tile[32][33];
  const float* S = (z == 0) ? Wq : (z == 1) ? Wk : (z == 2) ? Wv : Wo;
  unsigned short* D = (z < 3) ? (WtQKV + (size_t)z * HID * HID) : WtO;
  const float scale = (z == 0) ? 0.125f : 1.0f;
  int r0 = blockIdx.y * 32, c0 = blockIdx.x * 32;
  int tx = threadIdx.x, ty = threadIdx.y;
#pragma unroll
  for (int k = 0; k < 4; k++)
    tile[ty + k * 8][tx] = S[(size_t)(r0 + ty + k * 8) * HID + c0 + tx];
  __syncthreads();
#pragma unroll
  for (int k = 0; k < 4; k++)
    D[(size_t)(c0 + ty + k * 8) * HID + r0 + tx] = f2bf(scale * tile[tx][ty + k * 8]);
}

// ---------------- GEMM: C[M,N] = A[M,K](bf16) * Bt[N,K](bf16)^T ----------------
// Tile (MI*32) x BN, K-step BK. 4 waves in 2x2; wave tile (MI*16) x (BN/2).
// DOUBLE-BUFFERED, prefetch-before-compute, ONE barrier per K-step.
// LDS row: KC=BK/8 chunks of 16B; slot kc holds global chunk g = kc ^ (r & 7)
// (full 8-chunk XOR swizzle -> frag ds_read_b128 is 2-way (free) vs 4-way).
// Staging keeps a LINEAR LDS dest (global_load_lds rule) with inverse-permuted
// global source; frag read for global chunk c of row r uses slot c ^ (r & 7).
// XCD-rect swizzle: lin&7 = XCD (dispatch heuristic); each XCD gets a contiguous
// RW x (XB/RW) rectangle of its XB blocks so A/B slices fit the 4 MB per-XCD L2.
// WPE = min waves/SIMD (occupancy request; caps VGPRs accordingly).
// OUT==0: f32 row-major. OUT==2: bf16 row-major for cols<2048, transposed
// uint2 into Vout for cols>=2048 (the V block of the QKV projection).
template <int MI, int BN, int BK, int GX, int RW, int XB, int WPE, int OUT>
__global__ __launch_bounds__(256, WPE) void gemm_bt(const unsigned short* __restrict__ A,
                                                    const unsigned short* __restrict__ Bt,
                                                    void* __restrict__ Cout,
                                                    unsigned short* __restrict__ Vout,
                                                    int M, int N, int K) {
  constexpr int NI = BN / 32;   // per-wave n-frags (wave covers BN/2 cols)
  constexpr int TM = MI * 32;   // block rows
  constexpr int KC = BK / 8;    // 16B chunks per LDS row
  static_assert(KC == 8, "8-chunk XOR swizzle requires BK=64");
  __shared__ unsigned short As[2][TM * BK];
  __shared__ unsigned short Bs[2][BN * BK];
  const int tid = threadIdx.x;
  const int lane = tid & 63;
  const int w = tid >> 6;
  const int wm = w >> 1, wn = w & 1;
  const int quad = lane >> 4, l16 = lane & 15;

  const int lin = blockIdx.x + GX * blockIdx.y;
  const int xcd = lin & 7, idx = lin >> 3;
  const int bx = (xcd & 3) * RW + (idx % RW);
  const int by = (xcd >> 2) * (XB / RW) + (idx / RW);
  const int bm = by * TM, bn = bx * BN;

  f32x4 acc[MI][NI] = {};

  auto stage = [&](int k0, int b) {
#pragma unroll
    for (int c = tid; c < TM * KC; c += 256) {
      int r = c / KC, kc = c % KC;
      int g = kc ^ (r & 7);
      gld_lds16(A + (size_t)(bm + r) * K + k0 + g * 8, &As[b][c * 8]);
    }
#pragma unroll
    for (int c = tid; c < BN * KC; c += 256) {
      int r = c / KC, kc = c % KC;
      int g = kc ^ (r & 7);
      gld_lds16(Bt + (size_t)(bn + r) * K + k0 + g * 8, &Bs[b][c * 8]);
    }
  };

  const int NT = K / BK;
  stage(0, 0);
  __syncthreads();

  for (int t = 0; t < NT; ++t) {
    if (t + 1 < NT) stage((t + 1) * BK, (t + 1) & 1);
    const unsigned short* AsB = &As[t & 1][0];
    const unsigned short* BsB = &Bs[t & 1][0];
#pragma unroll
    for (int ks = 0; ks < BK / 32; ks++) {
      bf16x8 af[MI], bfr[NI];
#pragma unroll
      for (int mi = 0; mi < MI; mi++) {
        int m = wm * (MI * 16) + mi * 16 + l16;
        af[mi] = *(const bf16x8*)(AsB + (m * KC + ((ks * 4 + quad) ^ (m & 7))) * 8);
      }
#pragma unroll
      for (int ni = 0; ni < NI; ni++) {
        int n = wn * (BN / 2) + ni * 16 + l16;
        bfr[ni] = *(const bf16x8*)(BsB + (n * KC + ((ks * 4 + quad) ^ (n & 7))) * 8);
      }
#pragma unroll
      for (int mi = 0; mi < MI; mi++)
#pragma unroll
        for (int ni = 0; ni < NI; ni++)
          acc[mi][ni] = __builtin_amdgcn_mfma_f32_16x16x32_bf16(af[mi], bfr[ni], acc[mi][ni], 0, 0, 0);
    }
    __syncthreads();
  }

#pragma unroll
  for (int mi = 0; mi < MI; mi++) {
#pragma unroll
    for (int ni = 0; ni < NI; ni++) {
      int row = bm + wm * (MI * 16) + mi * 16 + quad * 4;
      int col = bn + wn * (BN / 2) + ni * 16 + l16;
      if (OUT == 0) {
#pragma unroll
        for (int r = 0; r < 4; r++)
          ((float*)Cout)[(size_t)(row + r) * N + col] = acc[mi][ni][r];
      } else {
        if (col < 2 * HID) {
#pragma unroll
          for (int r = 0; r < 4; r++)
            ((unsigned short*)Cout)[(size_t)(row + r) * N + col] = f2bf(acc[mi][ni][r]);
        } else {
          *(uint2*)(Vout + (size_t)(col - 2 * HID) * SEQ + row) =
              make_uint2(pkbf(acc[mi][ni][0], acc[mi][ni][1]),
                         pkbf(acc[mi][ni][2], acc[mi][ni][3]));
        }
      }
    }
  }
}

// ---------------- sparse flash attention (S^T form, fixed-max softmax) ----------------
// grid (SEQ/64, NH) linearized; XCD-aware remap: lin%8 selects the XCD so each
// XCD gets contiguous q-block runs whose K/V slices stay L2-resident.
// Double-buffered K/V tiles: staging for tile t+1 issues before computing tile
// t; ONE barrier per tile (buffer B=(t+1)&1 was last read at t-1, whose barrier
// fences it) -> vmcnt drain overlaps a full tile of compute. LDS 41 KB, 3/CU.
// Wave w handles q rows [qbase+w*16,+16). S^T = K·Q^T so C-layout row=j, col=i:
// lsum per-lane f32 scalar, P^T packs via v_cvt_pk_bf16_f32, O^T -> uint2 store.
// Q pre-scaled by 1/sqrt(HD); no exp clamp (scores ~N(0,1), max ~5.5 sigma).
// K/V tiles use the same full 8-chunk XOR swizzle as gemm_bt (slot = chunk ^
// (row & 7)) -> frag ds_read_b128 is 2-way (free) instead of 4-way conflicted.
__global__ __launch_bounds__(256, 3) void attn_sparse(const unsigned short* __restrict__ QKV,
                                                      const unsigned short* __restrict__ VtG,
                                                      unsigned short* __restrict__ AttO) {
  __shared__ unsigned short Ks[2][64 * 64];  // K tile [j][d], swizzled chunks
  __shared__ unsigned short Vt[2][64 * 64];  // V^T tile [d][j], swizzled chunks
  __shared__ unsigned short Pw[4][16 * 72];  // per-wave P^T as [i][j], stride 72
  const int lin = blockIdx.x + 32 * blockIdx.y;
  const int xcd = lin & 7, slot = lin >> 3;
  const int h = slot >> 2;
  const int qbase = (xcd * 4 + (slot & 3)) * 64;
  const int tid = threadIdx.x;
  const int lane = tid & 63, w = tid >> 6;
  const int quad = lane >> 4, l16 = lane & 15;
  const int qrow0 = qbase + w * 16;
  unsigned short* pws = &Pw[w][0];

  // Q B-fragment: lane = col i = l16, k = d = ks*32 + quad*8 + jj
  bf16x8 aq[2];
  {
    const unsigned short* qp = QKV + (size_t)(qrow0 + l16) * QKVLD + h * HD + quad * 8;
    aq[0] = *(const bf16x8*)qp;
    aq[1] = *(const bf16x8*)(qp + 32);
  }

  f32x4 accO[4] = {};
  float lsum = 0.f;

  const int jlo = (qbase >= 512) ? (qbase - 512) : 0;
  const int ng = (jlo > 0) ? ((jlo + 511) >> 9) : 0;  // global cols below window
  const int ntl = ((qbase - jlo) >> 6) + 1;           // local 64-wide tiles

  auto stage = [&](int j0, int b) {
#pragma unroll
    for (int c = tid; c < 512; c += 256) {
      int r = c >> 3, kc = c & 7;
      int g = kc ^ (r & 7);
      gld_lds16(QKV + (size_t)(j0 + r) * QKVLD + HID + h * HD + g * 8, &Ks[b][c * 8]);
      gld_lds16(VtG + (size_t)(h * HD + r) * SEQ + j0 + g * 8, &Vt[b][c * 8]);
    }
  };

  stage(jlo, 0);
  __syncthreads();

  for (int t = 0; t < ntl; t++) {
    if (t + 1 < ntl) stage(jlo + (t + 1) * 64, (t + 1) & 1);
    const unsigned short* KsB = Ks[t & 1];
    const unsigned short* VtB = Vt[t & 1];
    const int j0 = jlo + t * 64;

    // S^T: A = K (m=j), B = Q (n=i)
    f32x4 s[4] = {};
#pragma unroll
    for (int nj = 0; nj < 4; nj++) {
      int row = nj * 16 + l16;
#pragma unroll
      for (int ks = 0; ks < 2; ks++) {
        bf16x8 ak = *(const bf16x8*)(KsB + (row * 8 + ((ks * 4 + quad) ^ (row & 7))) * 8);
        s[nj] = __builtin_amdgcn_mfma_f32_16x16x32_bf16(ak, aq[ks], s[nj], 0, 0, 0);
      }
    }

    const bool isdiag = (t == ntl - 1);
    const bool istrail = (t == 0) && (qbase >= 512);
    const int trailg = (istrail && ((j0 & 511) == 0)) ? 1 : 0;
    const int db = qrow0 + l16 - j0 - quad * 4;  // i-j = db - nj*16 - r
#pragma unroll
    for (int nj = 0; nj < 4; nj++) {
      float p[4];
#pragma unroll
      for (int r = 0; r < 4; r++) {
        float x = s[nj][r];
        int d = db - nj * 16 - r;
        bool valid = true;
        if (isdiag) valid = (d >= 0);
        else if (istrail) valid = (d <= 512) || (trailg && (nj * 16 + quad * 4 + r) == 0);
        x = valid ? x : -1e30f;  // exp -> 0
        p[r] = __expf(x);
        lsum += p[r];
      }
      *(uint2*)(pws + l16 * 72 + nj * 16 + quad * 4) =
          make_uint2(pkbf(p[0], p[1]), pkbf(p[2], p[3]));
    }

    // O^T += V^T * P^T (within-wave LDS dependency; no barrier needed)
#pragma unroll
    for (int kk = 0; kk < 2; kk++) {
      bf16x8 bp = *(const bf16x8*)(pws + l16 * 72 + kk * 32 + quad * 8);
#pragma unroll
      for (int nd = 0; nd < 4; nd++) {
        int row = nd * 16 + l16;
        bf16x8 av = *(const bf16x8*)(VtB + (row * 8 + ((kk * 4 + quad) ^ (row & 7))) * 8);
        accO[nd] = __builtin_amdgcn_mfma_f32_16x16x32_bf16(av, bp, accO[nd], 0, 0, 0);
      }
    }
    __syncthreads();  // one barrier/tile: drains prefetch, fences both buffers
  }

  // ---- compact global tile last (order-free softmax; buffers fenced by loop) ----
  if (ng > 0) {
    if (tid < ng * 8) {  // K rows c<ng at j=512c
      int r = tid >> 3, kc = tid & 7;
      int g = kc ^ (r & 7);
      *(uint4*)(&Ks[0][tid * 8]) =
          *(const uint4*)(QKV + ((size_t)r << 9) * QKVLD + HID + h * HD + g * 8);
    }
    if (tid < ng * 64) {  // V^T cols c<ng (elem (d,c): chunk 0 -> slot d&7, offset c)
      int d = tid & 63, c = tid >> 6;
      Vt[0][(d * 8 + (d & 7)) * 8 + c] = VtG[(size_t)(h * HD + d) * SEQ + ((size_t)c << 9)];
    }
    __syncthreads();
    f32x4 s0 = {};
#pragma unroll
    for (int ks = 0; ks < 2; ks++) {
      bf16x8 ak = *(const bf16x8*)(&Ks[0][(l16 * 8 + ((ks * 4 + quad) ^ (l16 & 7))) * 8]);
      s0 = __builtin_amdgcn_mfma_f32_16x16x32_bf16(ak, aq[ks], s0, 0, 0, 0);
    }
    float p[4];
#pragma unroll
    for (int r = 0; r < 4; r++) {
      p[r] = ((quad * 4 + r) < ng) ? __expf(s0[r]) : 0.f;
      lsum += p[r];
    }
    *(uint2*)(pws + l16 * 72 + quad * 4) = make_uint2(pkbf(p[0], p[1]), pkbf(p[2], p[3]));
    *(uint2*)(pws + l16 * 72 + 16 + quad * 4) = make_uint2(0, 0);  // zero j in [16,32)
    bf16x8 bp = *(const bf16x8*)(pws + l16 * 72 + quad * 8);  // kk=0 only (j<32)
#pragma unroll
    for (int nd = 0; nd < 4; nd++) {
      int row = nd * 16 + l16;
      bf16x8 av = *(const bf16x8*)(&Vt[0][(row * 8 + (quad ^ (row & 7))) * 8]);
      accO[nd] = __builtin_amdgcn_mfma_f32_16x16x32_bf16(av, bp, accO[nd], 0, 0, 0);
    }
  }

  // ---- reduce l across quads, normalize, vectorized store ----
  lsum += __shfl_xor(lsum, 16);
  lsum += __shfl_xor(lsum, 32);
  const float rl = 1.0f / lsum;
  const int i = qrow0 + l16;
#pragma unroll
  for (int nd = 0; nd < 4; nd++) {
    *(uint2*)(AttO + (size_t)i * HID + h * HD + nd * 16 + quad * 4) =
        make_uint2(pkbf(accO[nd][0] * rl, accO[nd][1] * rl),
                   pkbf(accO[nd][2] * rl, accO[nd][3] * rl));
  }
}

extern "C" void kernel_launch(void* const* d_in, const int* in_sizes, int n_in,
                              void* d_out, int out_size, void* d_ws, size_t ws_size,
                              hipStream_t stream) {
  const float* X  = (const float*)d_in[0];
  const float* Wq = (const float*)d_in[1];
  const float* Wk = (const float*)d_in[2];
  const float* Wv = (const float*)d_in[3];
  const float* Wo = (const float*)d_in[4];
  float* out = (float*)d_out;

  unsigned short* Xb    = (unsigned short*)d_ws;                  // 2048x1024
  unsigned short* WtQKV = Xb + (size_t)SEQ * HID;                 // 3072x1024
  unsigned short* WtO   = WtQKV + (size_t)QKVLD * HID;            // 1024x1024
  unsigned short* QKV   = WtO + (size_t)HID * HID;                // 2048x3072 (V block unused)
  unsigned short* VtG   = QKV + (size_t)SEQ * QKVLD;              // 1024x2048 (V transposed)
  unsigned short* AttO  = VtG + (size_t)HID * SEQ;                // 2048x1024

  prep<<<dim3(32, 32, 5), dim3(32, 8), 0, stream>>>(X, Wq, Wk, Wv, Wo, Xb, WtQKV, WtO);

  // QKV: 128x96 tiles BK=64 double-buffered (56 KB LDS, WPE=2 -> 2 blocks/CU),
  // grid 16x32=512. XCD rect 8x8 (A 2MB + B 1.5MB per L2).
  gemm_bt<4, 96, 64, 32, 8, 64, 2, 2><<<dim3(32, 16), dim3(256), 0, stream>>>(
      Xb, WtQKV, QKV, VtG, SEQ, QKVLD, HID);

  attn_sparse<<<dim3(SEQ / 64, NH), dim3(256), 0, stream>>>(QKV, VtG, AttO);

  // out-proj: 64x64 tiles BK=64 double-buffered (32 KB LDS), grid 16x32=512
  // (2/CU), one barrier per K-step, XCD rect 4x16 (A 2MB + B 0.5MB)
  gemm_bt<2, 64, 64, 16, 4, 64, 2, 0><<<dim3(16, 32), dim3(256), 0, stream>>>(
      AttO, WtO, out, nullptr, SEQ, HID, HID);
}